// Round 5
// baseline (87.555 us; speedup 1.0000x reference)
//
#include <hip/hip_runtime.h>
#include <hip/hip_bf16.h>
#include <cstdint>
#include <cstddef>

typedef short short8 __attribute__((ext_vector_type(8)));
typedef float f32x4 __attribute__((ext_vector_type(4)));

constexpr int Nrows = 8192;   // rows of a
constexpr int Mrows = 8192;   // rows of b
constexpr int Dim   = 64;     // feature dim (K)

// ---------------------------------------------------------------------------
// Kernel 1: per-row L2 norm, scale row to unit length, cast to bf16 (RNE).
// (unchanged from R1 — proven)
// ---------------------------------------------------------------------------
__global__ __launch_bounds__(256) void cos_norm_scale(
    const float* __restrict__ a, const float* __restrict__ b,
    short* __restrict__ as_, short* __restrict__ bs_) {
  int gid = blockIdx.x * 256 + threadIdx.x;
  int row = gid >> 4;      // 16 threads per row
  int sub = gid & 15;      // which float4 of the row
  const float* src = a;
  short* dst = as_;
  if (row >= Nrows) { src = b; dst = bs_; row -= Nrows; }

  float4 v = reinterpret_cast<const float4*>(src + (size_t)row * Dim)[sub];
  float ss = v.x * v.x + v.y * v.y + v.z * v.z + v.w * v.w;
  ss += __shfl_xor(ss, 1);
  ss += __shfl_xor(ss, 2);
  ss += __shfl_xor(ss, 4);
  ss += __shfl_xor(ss, 8);
  float scale = rsqrtf(ss);

  float sv[4] = {v.x * scale, v.y * scale, v.z * scale, v.w * scale};
  short4 o;
  short* op = reinterpret_cast<short*>(&o);
#pragma unroll
  for (int i = 0; i < 4; ++i) {
    uint32_t u = __float_as_uint(sv[i]);
    u += 0x7fffu + ((u >> 16) & 1u);   // RNE to bf16
    op[i] = (short)(u >> 16);
  }
  reinterpret_cast<short4*>(dst + (size_t)row * Dim)[sub] = o;
}

// ---------------------------------------------------------------------------
// Kernel 2: C = A_unit @ B_unit^T via mfma_f32_16x16x32_bf16.
// Geometry change vs R1: block tile 16 rows x 1024 cols (4 waves side by
// side, each wave 16x256 = 16 fragments of 16x16, acc = 64 VGPR).
// Consecutive blocks (tn fast) tile one 16-row band contiguously, so the
// aggregate write stream per band is row-sequential -> long HBM bursts.
//
// Fragment layouts (gfx950, HW-verified):
//   A/B in : lane l holds 8 contiguous k-elems: row=l&15, k=(l>>4)*8 .. +7
//   C/D out: col = l&15, row = (l>>4)*4 + reg
// ---------------------------------------------------------------------------
__global__ __launch_bounds__(256) void cos_gemm(
    const short* __restrict__ A, const short* __restrict__ B,
    float* __restrict__ C) {
  int bid = blockIdx.x;
  int tm = bid >> 3;             // 512 row-bands of 16
  int tn = bid & 7;              // 8 col-panels of 1024 (fast -> band-contig)
  int wid  = threadIdx.x >> 6;   // 0..3
  int lane = threadIdx.x & 63;

  int R0 = tm * 16;                    // 16 output rows for the whole block
  int C0 = tn * 1024 + wid * 256;      // this wave's 256-col slice

  int lrow = lane & 15;
  int lk8  = (lane >> 4) * 8;

  f32x4 acc[16] = {};

#pragma unroll
  for (int s = 0; s < 2; ++s) {        // K steps of 32
    short8 af = *reinterpret_cast<const short8*>(
        A + (size_t)(R0 + lrow) * Dim + s * 32 + lk8);
    short8 bf[16];
#pragma unroll
    for (int j = 0; j < 16; ++j)
      bf[j] = *reinterpret_cast<const short8*>(
          B + (size_t)(C0 + j * 16 + lrow) * Dim + s * 32 + lk8);
#pragma unroll
    for (int j = 0; j < 16; ++j)
      acc[j] = __builtin_amdgcn_mfma_f32_16x16x32_bf16(af, bf[j], acc[j], 0, 0, 0);
  }

  // ---- epilogue: scalar stores, columns fastest -> row-sequential stream ----
  int crow = (lane >> 4) * 4;    // base row (0,4,8,12) per lane group
  int ccol = lane & 15;
#pragma unroll
  for (int r = 0; r < 4; ++r) {
#pragma unroll
    for (int j = 0; j < 16; ++j) {
      C[(size_t)(R0 + crow + r) * Mrows + (C0 + j * 16 + ccol)] = acc[j][r];
    }
  }
}

// ---------------------------------------------------------------------------
extern "C" void kernel_launch(void* const* d_in, const int* in_sizes, int n_in,
                              void* d_out, int out_size, void* d_ws, size_t ws_size,
                              hipStream_t stream) {
  const float* a = (const float*)d_in[0];
  const float* b = (const float*)d_in[1];
  float* out = (float*)d_out;

  short* as_ = (short*)d_ws;                       // 8192*64 bf16 = 1 MB
  short* bs_ = as_ + (size_t)Nrows * Dim;          // next 1 MB

  cos_norm_scale<<<1024, 256, 0, stream>>>(a, b, as_, bs_);
  // 512 row-bands x 8 col-panels = 4096 blocks
  cos_gemm<<<4096, 256, 0, stream>>>(as_, bs_, out);
}

// Round 6
// 62.905 us; speedup vs baseline: 1.3919x; 1.3919x over previous
//
#include <hip/hip_runtime.h>
#include <hip/hip_bf16.h>
#include <cstdint>
#include <cstddef>

typedef short short8 __attribute__((ext_vector_type(8)));
typedef float f32x4 __attribute__((ext_vector_type(4)));

constexpr int Nrows = 8192;   // rows of a
constexpr int Mrows = 8192;   // rows of b
constexpr int Dim   = 64;     // feature dim (K)

// ---------------------------------------------------------------------------
// Kernel 1: per-row L2 norm, scale row to unit length, cast to bf16 (RNE).
// (unchanged — proven)
// ---------------------------------------------------------------------------
__global__ __launch_bounds__(256) void cos_norm_scale(
    const float* __restrict__ a, const float* __restrict__ b,
    short* __restrict__ as_, short* __restrict__ bs_) {
  int gid = blockIdx.x * 256 + threadIdx.x;
  int row = gid >> 4;      // 16 threads per row
  int sub = gid & 15;      // which float4 of the row
  const float* src = a;
  short* dst = as_;
  if (row >= Nrows) { src = b; dst = bs_; row -= Nrows; }

  float4 v = reinterpret_cast<const float4*>(src + (size_t)row * Dim)[sub];
  float ss = v.x * v.x + v.y * v.y + v.z * v.z + v.w * v.w;
  ss += __shfl_xor(ss, 1);
  ss += __shfl_xor(ss, 2);
  ss += __shfl_xor(ss, 4);
  ss += __shfl_xor(ss, 8);
  float scale = rsqrtf(ss);

  float sv[4] = {v.x * scale, v.y * scale, v.z * scale, v.w * scale};
  short4 o;
  short* op = reinterpret_cast<short*>(&o);
#pragma unroll
  for (int i = 0; i < 4; ++i) {
    uint32_t u = __float_as_uint(sv[i]);
    u += 0x7fffu + ((u >> 16) & 1u);   // RNE to bf16
    op[i] = (short)(u >> 16);
  }
  reinterpret_cast<short4*>(dst + (size_t)row * Dim)[sub] = o;
}

// ---------------------------------------------------------------------------
// Kernel 2: identical to the R1 (61.5us) kernel except the blockIdx->tile
// mapping: band tm is pinned to XCD tm%8 (round-robin dispatch assumption),
// so each XCD's 4MB L2 owns one 128-row output band (4MB) and drains whole
// 32KB rows to HBM instead of scattered 512B chunks.
//   i%8   -> XCD slot (low 3 bits of tm)
//   i>>9  -> high 3 bits of tm
//   (i>>3)&63 -> tn (column tile, fast within a band)
// Bijective over 4096 blocks.
//
// Fragment layouts (gfx950, HW-verified):
//   A/B in : lane l holds 8 contiguous k-elems: row=l&15, k=(l>>4)*8 .. +7
//   C/D out: col = l&15, row = (l>>4)*4 + reg
// ---------------------------------------------------------------------------
__global__ __launch_bounds__(256) void cos_gemm(
    const short* __restrict__ A, const short* __restrict__ B,
    float* __restrict__ C) {
  int i = blockIdx.x;
  int tm = (i & 7) + 8 * (i >> 9);   // band index, pinned per-XCD
  int tn = (i >> 3) & 63;            // column tile, fast
  int wid  = threadIdx.x >> 6;
  int lane = threadIdx.x & 63;
  int wr = wid >> 1, wc = wid & 1;

  int R0 = tm * 128 + wr * 64;
  int C0 = tn * 128 + wc * 64;

  int lrow = lane & 15;
  int lk8  = (lane >> 4) * 8;

  f32x4 acc[4][4] = {};

#pragma unroll
  for (int s = 0; s < 2; ++s) {        // K steps of 32
    short8 af[4], bf[4];
#pragma unroll
    for (int i4 = 0; i4 < 4; ++i4)
      af[i4] = *reinterpret_cast<const short8*>(
          A + (size_t)(R0 + i4 * 16 + lrow) * Dim + s * 32 + lk8);
#pragma unroll
    for (int j = 0; j < 4; ++j)
      bf[j] = *reinterpret_cast<const short8*>(
          B + (size_t)(C0 + j * 16 + lrow) * Dim + s * 32 + lk8);
#pragma unroll
    for (int i4 = 0; i4 < 4; ++i4)
#pragma unroll
      for (int j = 0; j < 4; ++j)
        acc[i4][j] = __builtin_amdgcn_mfma_f32_16x16x32_bf16(
            af[i4], bf[j], acc[i4][j], 0, 0, 0);
  }

  int crow = (lane >> 4) * 4;
  int ccol = lane & 15;
#pragma unroll
  for (int i4 = 0; i4 < 4; ++i4) {
#pragma unroll
    for (int j = 0; j < 4; ++j) {
      float* p = C + (size_t)(R0 + i4 * 16 + crow) * Mrows + (C0 + j * 16 + ccol);
#pragma unroll
      for (int r = 0; r < 4; ++r)
        p[(size_t)r * Mrows] = acc[i4][j][r];
    }
  }
}

// ---------------------------------------------------------------------------
extern "C" void kernel_launch(void* const* d_in, const int* in_sizes, int n_in,
                              void* d_out, int out_size, void* d_ws, size_t ws_size,
                              hipStream_t stream) {
  const float* a = (const float*)d_in[0];
  const float* b = (const float*)d_in[1];
  float* out = (float*)d_out;

  short* as_ = (short*)d_ws;                       // 8192*64 bf16 = 1 MB
  short* bs_ = as_ + (size_t)Nrows * Dim;          // next 1 MB

  cos_norm_scale<<<1024, 256, 0, stream>>>(a, b, as_, bs_);
  cos_gemm<<<4096, 256, 0, stream>>>(as_, bs_, out);
}